// Round 15
// baseline (124.879 us; speedup 1.0000x reference)
//
#include <hip/hip_runtime.h>

// DualBiPlane R15: drop the int8 conv stage entirely — gather f32 planes
// directly in the pinned-flat interp.
//
// R14 (122 us) proved: XCD-pinned static bin mapping + flat one-item-per-
// thread + 4-lanes/record. With pinning, each XCD holds ONE bin at a time;
// an f32 bin (100 rows x 400 x 16ch x 4B) = 2.56 MB < 4 MB L2 -> int8
// compression is no longer needed for residency. Removing conv saves
// 82 MB read + 20.5 MB write + one launch; interp fetch rises ~40 MB
// (compulsory f32 planes). Quantization error also disappears.
//
// Pipeline: memset(cursor, 128B) -> k_scatter (8B records, fixed-capacity
// bins, block-aggregated) -> k_interp_pin_flat (f32 gathers).

typedef float f32x4 __attribute__((ext_vector_type(4)));
typedef unsigned int u32;
typedef unsigned long long u64;

constexpr int RES = 400;
constexpr int LCH = 16;
constexpr long long PLANE_STRIDE = (long long)RES * RES * LCH;   // 2,560,000
constexpr long long PLANE_ELEMS  = 4 * PLANE_STRIDE;             // per family

constexpr int NSLICE = 4;             // 100-row slices
constexpr int BINS_F = 4 * NSLICE;    // 16 bins per family
constexpr int NBINS  = 2 * BINS_F;    // 32 (A: 0..15, B: 16..31)
constexpr int PTS_PER_BLOCK = 1024;   // scatter: 256 thr x 4 pts

__device__ __forceinline__ float edge(float f) {
    return (f == (float)RES) ? (float)(RES - 1) : f;
}
__device__ __forceinline__ u32 quant(float f) { return (u32)(edge(f) * 2048.0f); }
__device__ __forceinline__ int slice_of(u32 qi) {        // i1/100, i1<400
    return (int)(((qi >> 11) * 41u) >> 12);
}
__device__ __forceinline__ u64 pack_rec(u32 qi, u32 qj, int p, int m) {
    return (u64)qi | ((u64)qj << 20) | ((u64)((u32)p | ((u32)m << 21)) << 40);
}

// ---- scatter: 8B records into fixed-capacity bins (base = bin*C),
// ---- block-aggregated (LDS count + one global atomic per bin per block) ----
__global__ __launch_bounds__(256) void k_scatter(
    const int* __restrict__ mArr, const float* __restrict__ h,
    const float* __restrict__ u, const float* __restrict__ v,
    u32* __restrict__ cursor, u64* __restrict__ rec, int N, u32 C)
{
    __shared__ u32 lh[NBINS];
    __shared__ u32 lbase[NBINS];
    int tid = threadIdx.x;
    if (tid < NBINS) lh[tid] = 0;
    __syncthreads();

    u64 ra[4], rb[4];
    int bina[4], binb[4];
    u32 la[4], lb[4];
    bool val[4];
    int base = blockIdx.x * PTS_PER_BLOCK;
    #pragma unroll
    for (int k = 0; k < 4; ++k) {
        int p = base + tid + k * 256;
        val[k] = (p < N);
        if (val[k]) {
            int m = mArr[p];
            u32 qi = quant((h[2ll * p]     + 1.0f) * 0.5f * (float)RES);
            u32 qj = quant((h[2ll * p + 1] + 1.0f) * 0.5f * (float)RES);
            ra[k] = pack_rec(qi, qj, p, m);
            bina[k] = m * NSLICE + slice_of(qi);
            la[k] = atomicAdd(&lh[bina[k]], 1u);
            u32 gi = quant(u[p] * (float)RES);
            u32 gj = quant(v[p] * (float)RES);
            rb[k] = pack_rec(gi, gj, p, m);
            binb[k] = BINS_F + m * NSLICE + slice_of(gi);
            lb[k] = atomicAdd(&lh[binb[k]], 1u);
        }
    }
    __syncthreads();
    if (tid < NBINS) lbase[tid] = atomicAdd(&cursor[tid], lh[tid]);
    __syncthreads();
    #pragma unroll
    for (int k = 0; k < 4; ++k) {
        if (val[k]) {
            u32 pa = lbase[bina[k]] + la[k];
            u32 pb = lbase[binb[k]] + lb[k];
            if (pa < C) rec[(u64)bina[k] * C + pa] = ra[k];   // ~48-sigma guard
            if (pb < C) rec[(u64)binb[k] * C + pb] = rb[k];
        }
    }
}

// ---- interp: flat, one item per thread, XCD-pinned static block->bin map.
// block g: slot = g&7, t = g>>3, binGroup = t/BPB, bin = slot + 8*binGroup.
// 4 adjacent lanes share a record: each lane gathers f32x4 (16B) per corner
// (64B contiguous per quad) and stores 16B -> 64B contiguous per quad. ----
__global__ __launch_bounds__(256) void k_interp_pin_flat(
    const u64* __restrict__ rec, const float* __restrict__ Fxy,
    const float* __restrict__ Fuv, const u32* __restrict__ cursor,
    float* __restrict__ out, u32 C, int BPB)
{
    int slot = blockIdx.x & 7;
    int t = blockIdx.x >> 3;
    int bg = (t >= 3 * BPB) ? 3 : (t >= 2 * BPB) ? 2 : (t >= BPB) ? 1 : 0;
    int j = t - bg * BPB;
    int bin = slot + 8 * bg;                 // 0..31
    int famB = bin >> 4;
    u32 cnt = cursor[bin];
    if (cnt > C) cnt = C;

    long long it = (long long)j * 256 + threadIdx.x;
    if (it >= (long long)cnt * 4) return;
    int q = (int)(it >> 2);
    int c = (int)(it & 3);

    u64 r = rec[(u64)bin * C + q];
    u32 qi = (u32)(r & 0xFFFFFu);
    u32 qj = (u32)((r >> 20) & 0xFFFFFu);
    u32 pm = (u32)(r >> 40);
    int p = (int)(pm & 0x1FFFFFu);
    int m = (int)(pm >> 21);

    int i1 = (int)(qi >> 11), j1 = (int)(qj >> 11);
    float ir = (float)(qi & 2047u) * (1.0f / 2048.0f);
    float jr = (float)(qj & 2047u) * (1.0f / 2048.0f);
    int i2 = (i1 + 1 == RES) ? 0 : i1 + 1;
    int j2 = (j1 + 1 == RES) ? 0 : j1 + 1;

    const float* __restrict__ F = famB ? Fuv : Fxy;
    const float* __restrict__ Fb = F + (long long)m * PLANE_STRIDE + c * 4;
    f32x4 g00 = *reinterpret_cast<const f32x4*>(Fb + (i1 * RES + j1) * LCH);
    f32x4 g10 = *reinterpret_cast<const f32x4*>(Fb + (i2 * RES + j1) * LCH);
    f32x4 g01 = *reinterpret_cast<const f32x4*>(Fb + (i1 * RES + j2) * LCH);
    f32x4 g11 = *reinterpret_cast<const f32x4*>(Fb + (i2 * RES + j2) * LCH);

    float omi = 1.0f - ir, omj = 1.0f - jr;
    f32x4 res = (g00 * omi + g10 * ir) * omj + (g01 * omi + g11 * ir) * jr;

    int halfOfs = famB << 4;
    __builtin_nontemporal_store(res,
        reinterpret_cast<f32x4*>(out + (long long)p * 32 + halfOfs + c * 4));
}

// ---- fallback: f32 simple (no ws) ----
__global__ __launch_bounds__(256) void dualbiplane_simple(
    const int* __restrict__ mArr, const float* __restrict__ h,
    const float* __restrict__ u, const float* __restrict__ v,
    const float* __restrict__ Fxy, const float* __restrict__ Fuv,
    float* __restrict__ out, int N)
{
    long long t = (long long)blockIdx.x * blockDim.x + threadIdx.x;
    int p = (int)(t >> 3);
    if (p >= N) return;
    int sub = (int)(t & 7);
    int mi = mArr[p];
    float fi, fj;
    const float* __restrict__ F;
    if (sub < 4) {
        fi = edge((h[2ll * p] + 1.0f) * 0.5f * (float)RES);
        fj = edge((h[2ll * p + 1] + 1.0f) * 0.5f * (float)RES);
        F = Fxy;
    } else {
        fi = edge(u[p] * (float)RES);
        fj = edge(v[p] * (float)RES);
        F = Fuv;
    }
    int i1 = (int)fi, j1 = (int)fj;
    float ir = fi - (float)i1, jr = fj - (float)j1;
    int i2 = (i1 + 1 == RES) ? 0 : i1 + 1;
    int j2 = (j1 + 1 == RES) ? 0 : j1 + 1;
    int c = (sub & 3) * 4;
    const float* __restrict__ Fb = F + (long long)mi * PLANE_STRIDE + c;
    f32x4 g00 = *reinterpret_cast<const f32x4*>(Fb + (i1 * RES + j1) * LCH);
    f32x4 g10 = *reinterpret_cast<const f32x4*>(Fb + (i2 * RES + j1) * LCH);
    f32x4 g01 = *reinterpret_cast<const f32x4*>(Fb + (i1 * RES + j2) * LCH);
    f32x4 g11 = *reinterpret_cast<const f32x4*>(Fb + (i2 * RES + j2) * LCH);
    float omi = 1.0f - ir, omj = 1.0f - jr;
    f32x4 res = (g00 * omi + g10 * ir) * omj + (g01 * omi + g11 * ir) * jr;
    __builtin_nontemporal_store(res, reinterpret_cast<f32x4*>(out + t * 4));
}

extern "C" void kernel_launch(void* const* d_in, const int* in_sizes, int n_in,
                              void* d_out, int out_size, void* d_ws, size_t ws_size,
                              hipStream_t stream)
{
    const int*   m   = (const int*)d_in[0];
    const float* h   = (const float*)d_in[1];
    const float* u   = (const float*)d_in[2];
    const float* v   = (const float*)d_in[3];
    const float* Fxy = (const float*)d_in[4];
    const float* Fuv = (const float*)d_in[5];
    float* out = (float*)d_out;
    int N = in_sizes[0];

    // fixed bin capacity: N/16 + 12.5% + 1024, rounded up to 64
    u32 C = (u32)((N + 15) / 16);
    C = C + C / 8 + 1024;
    C = (C + 63) & ~63u;
    int BPB = (int)(C / 64);              // blocks per bin (4C items / 1024)

    size_t offRec  = 0;
    size_t offCur  = offRec + (size_t)NBINS * C * 8;
    size_t need    = offCur + NBINS * 4;

    if (ws_size < need) {
        long long total = (long long)N * 8;
        dualbiplane_simple<<<(unsigned)((total + 255) / 256), 256, 0, stream>>>(
            m, h, u, v, Fxy, Fuv, out, N);
        return;
    }

    char* ws     = (char*)d_ws;
    u64*  rec    = (u64*)(ws + offRec);
    u32*  cursor = (u32*)(ws + offCur);

    hipMemsetAsync(cursor, 0, NBINS * 4, stream);

    unsigned nb = (unsigned)((N + PTS_PER_BLOCK - 1) / PTS_PER_BLOCK);
    k_scatter<<<nb, 256, 0, stream>>>(m, h, u, v, cursor, rec, N, C);
    k_interp_pin_flat<<<(unsigned)(NBINS * BPB), 256, 0, stream>>>(
        rec, Fxy, Fuv, cursor, out, C, BPB);
}